// Round 1
// baseline (518.721 us; speedup 1.0000x reference)
//
#include <hip/hip_runtime.h>

#define S_LEN 2048
#define D_KD  64
#define NKT   32          // S / 64 k-tiles
#define NBH   64          // B*H

typedef __attribute__((ext_vector_type(8))) short short8;   // 8 bf16 (4 VGPRs)
typedef __attribute__((ext_vector_type(4))) float f32x4;    // MFMA C/D

// ---- bf16 round-to-nearest-even from f32 ----
__device__ __forceinline__ unsigned short f2bf(float f) {
    unsigned u = __builtin_bit_cast(unsigned, f);
    return (unsigned short)((u + 0x7fffu + ((u >> 16) & 1u)) >> 16);
}

// ---- XOR swizzle for [64][64] bf16 tiles (row stride 128B).
// Flips the 16B-chunk index (bits 4..6) with row bits so strided
// ds_read_b128 fragment reads are conflict-free.  Bijective per row.
__device__ __forceinline__ unsigned swz(int row, int bytecol) {
    return (unsigned)(row * 128 + bytecol) ^
           (((((unsigned)row & 7u) ^ ((unsigned)row >> 3)) & 7u) << 4);
}

// Stage a contiguous 64x64 f32 tile -> bf16 row-major swizzled LDS.
__device__ __forceinline__ void stage_rm(const float* __restrict__ g,
                                         unsigned char* lds, int tid) {
#pragma unroll
    for (int j = 0; j < 4; j++) {
        int idx = j * 1024 + tid * 4;
        int row = idx >> 6, col = idx & 63;
        float4 v = *(const float4*)(g + idx);
        ushort4 b = make_ushort4(f2bf(v.x), f2bf(v.y), f2bf(v.z), f2bf(v.w));
        *(ushort4*)(lds + swz(row, col * 2)) = b;
    }
}

// Stage a contiguous 64x64 f32 tile TRANSPOSED (lds[row=dcol][col=key]).
__device__ __forceinline__ void stage_tr(const float* __restrict__ g,
                                         unsigned char* lds, int tid) {
#pragma unroll
    for (int j = 0; j < 4; j++) {
        int idx = j * 1024 + tid * 4;
        int row = idx >> 6, col = idx & 63;   // row=key, col=dcol base
        float4 v = *(const float4*)(g + idx);
        *(unsigned short*)(lds + swz(col + 0, row * 2)) = f2bf(v.x);
        *(unsigned short*)(lds + swz(col + 1, row * 2)) = f2bf(v.y);
        *(unsigned short*)(lds + swz(col + 2, row * 2)) = f2bf(v.z);
        *(unsigned short*)(lds + swz(col + 3, row * 2)) = f2bf(v.w);
    }
}

// 64x64 QK^T for this wave's 16-row slice: acc[nt] = Q[16wv..][*] . K[16nt..][*]^T
__device__ __forceinline__ void qkt(const unsigned char* Qs, const unsigned char* Ks,
                                    int wv, int lr, int lg, f32x4 acc[4]) {
    short8 a0 = *(const short8*)(Qs + swz(16 * wv + lr, 16 * lg));
    short8 a1 = *(const short8*)(Qs + swz(16 * wv + lr, 16 * lg + 64));
#pragma unroll
    for (int nt = 0; nt < 4; nt++) {
        short8 b0 = *(const short8*)(Ks + swz(16 * nt + lr, 16 * lg));
        short8 b1 = *(const short8*)(Ks + swz(16 * nt + lr, 16 * lg + 64));
        acc[nt] = __builtin_amdgcn_mfma_f32_16x16x32_bf16(a0, b0, acc[nt], 0, 0, 0);
        acc[nt] = __builtin_amdgcn_mfma_f32_16x16x32_bf16(a1, b1, acc[nt], 0, 0, 0);
    }
}

__global__ __launch_bounds__(256) void attn_fused(
    const float* __restrict__ Q, const float* __restrict__ K,
    const float* __restrict__ V, const float* __restrict__ M,
    float* __restrict__ out) {
    __shared__ unsigned char Qs[8192];
    __shared__ unsigned char Ks[8192];
    __shared__ unsigned char Vs[8192];   // transposed: [dcol][key]
    __shared__ unsigned char Ps[8192];

    const int tid = threadIdx.x;
    const int wv = tid >> 6, lane = tid & 63, lr = lane & 15, lg = lane >> 4;
    const int qt = blockIdx.x & 31, bh = blockIdx.x >> 5;

    const float* Qg = Q + ((size_t)bh * S_LEN + qt * 64) * D_KD;
    const float* Kg = K + (size_t)bh * S_LEN * D_KD;
    const float* Vg = V + (size_t)bh * S_LEN * D_KD;
    float* ctxg = out + ((size_t)bh * S_LEN + qt * 64) * D_KD;
    float* attng = out + (size_t)NBH * S_LEN * D_KD +
                   (size_t)bh * S_LEN * S_LEN + (size_t)(qt * 64) * S_LEN;
    const float* Mg = M + (size_t)(qt * 64) * S_LEN;  // mask broadcast over bh

    stage_rm(Qg, Qs, tid);                // Q tile persists for both passes

    f32x4 accc[4] = {};                   // unnormalized context, rows 4lg+r, cols 16nt+lr
    float rs[4] = {0.f, 0.f, 0.f, 0.f};   // rowsum of exp*mask

    // ---------------- pass 1: rowsum + context ----------------
    for (int t = 0; t < NKT; t++) {
        stage_rm(Kg + (size_t)t * 64 * D_KD, Ks, tid);
        stage_tr(Vg + (size_t)t * 64 * D_KD, Vs, tid);
        __syncthreads();

        f32x4 acc[4] = {};
        qkt(Qs, Ks, wv, lr, lg, acc);

        // exp * mask, rowsum, stage P (bf16) for PV
#pragma unroll
        for (int r = 0; r < 4; r++) {
            const int row = 16 * wv + 4 * lg + r;
            const float* mrow = Mg + (size_t)row * S_LEN + t * 64;
#pragma unroll
            for (int nt = 0; nt < 4; nt++) {
                float e = __expf(acc[nt][r] * 0.125f) * mrow[16 * nt + lr];
                rs[r] += e;
                *(unsigned short*)(Ps + swz(row, (16 * nt + lr) * 2)) = f2bf(e);
            }
        }
        __syncthreads();   // P visible (also orders vs other waves' staging)

        // PV: accc += P(16 rows x 64) @ V(64 x 64)
#pragma unroll
        for (int kt = 0; kt < 2; kt++) {
            short8 pa = *(const short8*)(Ps + swz(16 * wv + lr, 16 * lg + 64 * kt));
#pragma unroll
            for (int nt = 0; nt < 4; nt++) {
                short8 vb = *(const short8*)(Vs + swz(16 * nt + lr, 16 * lg + 64 * kt));
                accc[nt] = __builtin_amdgcn_mfma_f32_16x16x32_bf16(pa, vb, accc[nt], 0, 0, 0);
            }
        }
        __syncthreads();   // done with Ks/Vs before next stage
    }

    // rowsum reduce across the 16 lanes of each lg group (rows 4lg+r)
    float inv[4];
#pragma unroll
    for (int r = 0; r < 4; r++) {
        float v = rs[r];
        v += __shfl_xor(v, 1);
        v += __shfl_xor(v, 2);
        v += __shfl_xor(v, 4);
        v += __shfl_xor(v, 8);
        inv[r] = 1.0f / (v + 1e-8f);
    }

    // context write
#pragma unroll
    for (int r = 0; r < 4; r++) {
        const int row = 16 * wv + 4 * lg + r;
#pragma unroll
        for (int nt = 0; nt < 4; nt++)
            ctxg[(size_t)row * D_KD + 16 * nt + lr] = accc[nt][r] * inv[r];
    }

    // ---------------- pass 2: recompute scores, write normalized attn ----------------
    for (int t = 0; t < NKT; t++) {
        __syncthreads();
        stage_rm(Kg + (size_t)t * 64 * D_KD, Ks, tid);
        __syncthreads();

        f32x4 acc[4] = {};
        qkt(Qs, Ks, wv, lr, lg, acc);

#pragma unroll
        for (int r = 0; r < 4; r++) {
            const int row = 16 * wv + 4 * lg + r;
            const float* mrow = Mg + (size_t)row * S_LEN + t * 64;
            float* arow = attng + (size_t)row * S_LEN + t * 64;
#pragma unroll
            for (int nt = 0; nt < 4; nt++) {
                float e = __expf(acc[nt][r] * 0.125f) * mrow[16 * nt + lr] * inv[r];
                __builtin_nontemporal_store(e, arow + 16 * nt + lr);
            }
        }
    }
}

extern "C" void kernel_launch(void* const* d_in, const int* in_sizes, int n_in,
                              void* d_out, int out_size, void* d_ws, size_t ws_size,
                              hipStream_t stream) {
    const float* Q = (const float*)d_in[0];
    const float* K = (const float*)d_in[1];
    const float* V = (const float*)d_in[2];
    const float* M = (const float*)d_in[3];
    float* out = (float*)d_out;
    attn_fused<<<dim3(NBH * 32), dim3(256), 0, stream>>>(Q, K, V, M, out);
}

// Round 5
// 511.621 us; speedup vs baseline: 1.0139x; 1.0139x over previous
//
// v4 — identical to v2/v3 (three prior benches died to infra: UnresponsiveContainer).
#include <hip/hip_runtime.h>

#define S_LEN 2048
#define D_KD  64
#define NKT   32          // S / 64 k-tiles
#define NBH   64          // B*H
#define KSEG  4           // kernel2: key segments per (bh,qt)

typedef __attribute__((ext_vector_type(8))) short short8;   // 8 bf16 (4 VGPRs)
typedef __attribute__((ext_vector_type(4))) float f32x4;    // MFMA C/D

// ---- bf16 round-to-nearest-even from f32 ----
__device__ __forceinline__ unsigned short f2bf(float f) {
    unsigned u = __builtin_bit_cast(unsigned, f);
    return (unsigned short)((u + 0x7fffu + ((u >> 16) & 1u)) >> 16);
}

// ---- XOR swizzle for [64][64] bf16 tiles (row stride 128B).
__device__ __forceinline__ unsigned swz(int row, int bytecol) {
    return (unsigned)(row * 128 + bytecol) ^
           (((((unsigned)row & 7u) ^ ((unsigned)row >> 3)) & 7u) << 4);
}

// Stage a contiguous 64x64 f32 tile -> bf16 row-major swizzled LDS.
__device__ __forceinline__ void stage_rm(const float* __restrict__ g,
                                         unsigned char* lds, int tid) {
#pragma unroll
    for (int j = 0; j < 4; j++) {
        int idx = j * 1024 + tid * 4;
        int row = idx >> 6, col = idx & 63;
        float4 v = *(const float4*)(g + idx);
        ushort4 b = make_ushort4(f2bf(v.x), f2bf(v.y), f2bf(v.z), f2bf(v.w));
        *(ushort4*)(lds + swz(row, col * 2)) = b;
    }
}

// Stage a contiguous 64x64 f32 tile TRANSPOSED (lds[row=dcol][col=key]).
// 4x4-block register transpose -> ushort4 LDS writes.
__device__ __forceinline__ void stage_tr(const float* __restrict__ g,
                                         unsigned char* lds, int tid) {
    const int br = tid >> 4;   // key block: rows 4br..4br+3
    const int bc = tid & 15;   // d block:   cols 4bc..4bc+3
    const float* gp = g + (4 * br) * 64 + 4 * bc;
    float4 v0 = *(const float4*)(gp + 0 * 64);
    float4 v1 = *(const float4*)(gp + 1 * 64);
    float4 v2 = *(const float4*)(gp + 2 * 64);
    float4 v3 = *(const float4*)(gp + 3 * 64);
    ushort4 c;
    c = make_ushort4(f2bf(v0.x), f2bf(v1.x), f2bf(v2.x), f2bf(v3.x));
    *(ushort4*)(lds + swz(4 * bc + 0, 8 * br)) = c;
    c = make_ushort4(f2bf(v0.y), f2bf(v1.y), f2bf(v2.y), f2bf(v3.y));
    *(ushort4*)(lds + swz(4 * bc + 1, 8 * br)) = c;
    c = make_ushort4(f2bf(v0.z), f2bf(v1.z), f2bf(v2.z), f2bf(v3.z));
    *(ushort4*)(lds + swz(4 * bc + 2, 8 * br)) = c;
    c = make_ushort4(f2bf(v0.w), f2bf(v1.w), f2bf(v2.w), f2bf(v3.w));
    *(ushort4*)(lds + swz(4 * bc + 3, 8 * br)) = c;
}

// 64x64 QK^T for this wave's 16-row slice.
__device__ __forceinline__ void qkt(const unsigned char* Qs, const unsigned char* Ks,
                                    int wv, int lr, int lg, f32x4 acc[4]) {
    short8 a0 = *(const short8*)(Qs + swz(16 * wv + lr, 16 * lg));
    short8 a1 = *(const short8*)(Qs + swz(16 * wv + lr, 16 * lg + 64));
#pragma unroll
    for (int nt = 0; nt < 4; nt++) {
        short8 b0 = *(const short8*)(Ks + swz(16 * nt + lr, 16 * lg));
        short8 b1 = *(const short8*)(Ks + swz(16 * nt + lr, 16 * lg + 64));
        acc[nt] = __builtin_amdgcn_mfma_f32_16x16x32_bf16(a0, b0, acc[nt], 0, 0, 0);
        acc[nt] = __builtin_amdgcn_mfma_f32_16x16x32_bf16(a1, b1, acc[nt], 0, 0, 0);
    }
}

// ---------------- kernel 1: context + inverse rowsums ----------------
__global__ __launch_bounds__(256) void attn_ctx(
    const float* __restrict__ Q, const float* __restrict__ K,
    const float* __restrict__ V, const float* __restrict__ M,
    float* __restrict__ out, float* __restrict__ invg) {
    __shared__ unsigned char Qs[8192];
    __shared__ unsigned char Ks[8192];
    __shared__ unsigned char Vs[8192];   // transposed: [dcol][key]
    __shared__ unsigned char Ps[8192];

    const int tid = threadIdx.x;
    const int wv = tid >> 6, lane = tid & 63, lr = lane & 15, lg = lane >> 4;
    const int qt = blockIdx.x & 31, bh = blockIdx.x >> 5;

    const float* Qg = Q + ((size_t)bh * S_LEN + qt * 64) * D_KD;
    const float* Kg = K + (size_t)bh * S_LEN * D_KD;
    const float* Vg = V + (size_t)bh * S_LEN * D_KD;
    float* ctxg = out + ((size_t)bh * S_LEN + qt * 64) * D_KD;
    const float* Mg = M + (size_t)(qt * 64) * S_LEN;  // mask broadcast over bh

    stage_rm(Qg, Qs, tid);

    f32x4 accc[4] = {};
    float rs[4] = {0.f, 0.f, 0.f, 0.f};

    for (int t = 0; t < NKT; t++) {
        stage_rm(Kg + (size_t)t * 64 * D_KD, Ks, tid);
        stage_tr(Vg + (size_t)t * 64 * D_KD, Vs, tid);
        __syncthreads();

        f32x4 acc[4] = {};
        qkt(Qs, Ks, wv, lr, lg, acc);

#pragma unroll
        for (int r = 0; r < 4; r++) {
            const int row = 16 * wv + 4 * lg + r;
            const float* mrow = Mg + (size_t)row * S_LEN + t * 64;
#pragma unroll
            for (int nt = 0; nt < 4; nt++) {
                float e = __expf(acc[nt][r] * 0.125f) * mrow[16 * nt + lr];
                rs[r] += e;
                *(unsigned short*)(Ps + swz(row, (16 * nt + lr) * 2)) = f2bf(e);
            }
        }
        __syncthreads();

#pragma unroll
        for (int kt = 0; kt < 2; kt++) {
            short8 pa = *(const short8*)(Ps + swz(16 * wv + lr, 16 * lg + 64 * kt));
#pragma unroll
            for (int nt = 0; nt < 4; nt++) {
                short8 vb = *(const short8*)(Vs + swz(16 * nt + lr, 16 * lg + 64 * kt));
                accc[nt] = __builtin_amdgcn_mfma_f32_16x16x32_bf16(pa, vb, accc[nt], 0, 0, 0);
            }
        }
        __syncthreads();
    }

    float inv[4];
#pragma unroll
    for (int r = 0; r < 4; r++) {
        float v = rs[r];
        v += __shfl_xor(v, 1);
        v += __shfl_xor(v, 2);
        v += __shfl_xor(v, 4);
        v += __shfl_xor(v, 8);
        inv[r] = 1.0f / (v + 1e-8f);
    }

    // context write
#pragma unroll
    for (int r = 0; r < 4; r++) {
        const int row = 16 * wv + 4 * lg + r;
#pragma unroll
        for (int nt = 0; nt < 4; nt++)
            ctxg[(size_t)row * D_KD + 16 * nt + lr] = accc[nt][r] * inv[r];
    }

    // inv write (one lane per row group)
    if (lr == 0) {
#pragma unroll
        for (int r = 0; r < 4; r++)
            invg[(size_t)bh * S_LEN + qt * 64 + 16 * wv + 4 * lg + r] = inv[r];
    }
}

// ---------------- kernel 2: stream normalized attn ----------------
__global__ __launch_bounds__(256) void attn_mat(
    const float* __restrict__ Q, const float* __restrict__ K,
    const float* __restrict__ M, const float* __restrict__ invg,
    float* __restrict__ out) {
    __shared__ unsigned char Qs[8192];
    __shared__ unsigned char Ks[8192];

    const int tid = threadIdx.x;
    const int wv = tid >> 6, lane = tid & 63, lr = lane & 15, lg = lane >> 4;
    const int ks = blockIdx.x & (KSEG - 1);
    const int qt = (blockIdx.x >> 2) & 31;
    const int bh = blockIdx.x >> 7;

    const float* Qg = Q + ((size_t)bh * S_LEN + qt * 64) * D_KD;
    const float* Kg = K + (size_t)bh * S_LEN * D_KD;
    const float* Mg = M + (size_t)(qt * 64) * S_LEN;
    float* attng = out + (size_t)NBH * S_LEN * D_KD +
                   (size_t)bh * S_LEN * S_LEN + (size_t)(qt * 64) * S_LEN;

    stage_rm(Qg, Qs, tid);

    float inv[4];
#pragma unroll
    for (int r = 0; r < 4; r++)
        inv[r] = invg[(size_t)bh * S_LEN + qt * 64 + 16 * wv + 4 * lg + r];

    const int nt_kt = S_LEN / (64 * KSEG);   // 8 k-tiles per block
    for (int kt = 0; kt < nt_kt; kt++) {
        const int key0 = ks * (S_LEN / KSEG) + kt * 64;
        if (kt) __syncthreads();
        stage_rm(Kg + (size_t)key0 * D_KD, Ks, tid);
        __syncthreads();

        f32x4 acc[4] = {};
        qkt(Qs, Ks, wv, lr, lg, acc);

#pragma unroll
        for (int r = 0; r < 4; r++) {
            const int row = 16 * wv + 4 * lg + r;
            const float* mrow = Mg + (size_t)row * S_LEN + key0;
            float* arow = attng + (size_t)row * S_LEN + key0;
#pragma unroll
            for (int nt = 0; nt < 4; nt++) {
                float e = __expf(acc[nt][r] * 0.125f) * mrow[16 * nt + lr] * inv[r];
                __builtin_nontemporal_store(e, arow + 16 * nt + lr);
            }
        }
    }
}

extern "C" void kernel_launch(void* const* d_in, const int* in_sizes, int n_in,
                              void* d_out, int out_size, void* d_ws, size_t ws_size,
                              hipStream_t stream) {
    const float* Q = (const float*)d_in[0];
    const float* K = (const float*)d_in[1];
    const float* V = (const float*)d_in[2];
    const float* M = (const float*)d_in[3];
    float* out = (float*)d_out;
    float* invg = (float*)d_ws;          // 64*2048 floats = 512 KB
    attn_ctx<<<dim3(NBH * 32), dim3(256), 0, stream>>>(Q, K, V, M, out, invg);
    attn_mat<<<dim3(NBH * 32 * KSEG), dim3(256), 0, stream>>>(Q, K, M, invg, out);
}

// Round 6
// 496.075 us; speedup vs baseline: 1.0457x; 1.0313x over previous
//
// v5: attn_ctx gets T14 register double-buffering (prefetch next K/V tile
//     during compute). attn_mat unchanged from v2 for clean attribution.
#include <hip/hip_runtime.h>

#define S_LEN 2048
#define D_KD  64
#define NKT   32          // S / 64 k-tiles
#define NBH   64          // B*H
#define KSEG  4           // kernel2: key segments per (bh,qt)

typedef __attribute__((ext_vector_type(8))) short short8;   // 8 bf16 (4 VGPRs)
typedef __attribute__((ext_vector_type(4))) float f32x4;    // MFMA C/D

// ---- bf16 round-to-nearest-even from f32 ----
__device__ __forceinline__ unsigned short f2bf(float f) {
    unsigned u = __builtin_bit_cast(unsigned, f);
    return (unsigned short)((u + 0x7fffu + ((u >> 16) & 1u)) >> 16);
}

// ---- XOR swizzle for [64][64] bf16 tiles (row stride 128B).
__device__ __forceinline__ unsigned swz(int row, int bytecol) {
    return (unsigned)(row * 128 + bytecol) ^
           (((((unsigned)row & 7u) ^ ((unsigned)row >> 3)) & 7u) << 4);
}

// ---- register-staged tile load/write (T14 split) ----
__device__ __forceinline__ void load_rm(const float* __restrict__ g,
                                        float4 r[4], int tid) {
#pragma unroll
    for (int j = 0; j < 4; j++) r[j] = *(const float4*)(g + j * 1024 + tid * 4);
}
__device__ __forceinline__ void write_rm(const float4 r[4],
                                         unsigned char* lds, int tid) {
#pragma unroll
    for (int j = 0; j < 4; j++) {
        int idx = j * 1024 + tid * 4;
        int row = idx >> 6, col = idx & 63;
        ushort4 b = make_ushort4(f2bf(r[j].x), f2bf(r[j].y), f2bf(r[j].z), f2bf(r[j].w));
        *(ushort4*)(lds + swz(row, col * 2)) = b;
    }
}
__device__ __forceinline__ void load_tr(const float* __restrict__ g,
                                        float4 r[4], int tid) {
    const int br = tid >> 4, bc = tid & 15;
    const float* gp = g + (4 * br) * 64 + 4 * bc;
#pragma unroll
    for (int j = 0; j < 4; j++) r[j] = *(const float4*)(gp + j * 64);
}
__device__ __forceinline__ void write_tr(const float4 r[4],
                                         unsigned char* lds, int tid) {
    const int br = tid >> 4, bc = tid & 15;
    ushort4 c;
    c = make_ushort4(f2bf(r[0].x), f2bf(r[1].x), f2bf(r[2].x), f2bf(r[3].x));
    *(ushort4*)(lds + swz(4 * bc + 0, 8 * br)) = c;
    c = make_ushort4(f2bf(r[0].y), f2bf(r[1].y), f2bf(r[2].y), f2bf(r[3].y));
    *(ushort4*)(lds + swz(4 * bc + 1, 8 * br)) = c;
    c = make_ushort4(f2bf(r[0].z), f2bf(r[1].z), f2bf(r[2].z), f2bf(r[3].z));
    *(ushort4*)(lds + swz(4 * bc + 2, 8 * br)) = c;
    c = make_ushort4(f2bf(r[0].w), f2bf(r[1].w), f2bf(r[2].w), f2bf(r[3].w));
    *(ushort4*)(lds + swz(4 * bc + 3, 8 * br)) = c;
}

// Stage a contiguous 64x64 f32 tile -> bf16 row-major swizzled LDS (kernel2).
__device__ __forceinline__ void stage_rm(const float* __restrict__ g,
                                         unsigned char* lds, int tid) {
    float4 r[4];
    load_rm(g, r, tid);
    write_rm(r, lds, tid);
}

// 64x64 QK^T for this wave's 16-row slice.
__device__ __forceinline__ void qkt(const unsigned char* Qs, const unsigned char* Ks,
                                    int wv, int lr, int lg, f32x4 acc[4]) {
    short8 a0 = *(const short8*)(Qs + swz(16 * wv + lr, 16 * lg));
    short8 a1 = *(const short8*)(Qs + swz(16 * wv + lr, 16 * lg + 64));
#pragma unroll
    for (int nt = 0; nt < 4; nt++) {
        short8 b0 = *(const short8*)(Ks + swz(16 * nt + lr, 16 * lg));
        short8 b1 = *(const short8*)(Ks + swz(16 * nt + lr, 16 * lg + 64));
        acc[nt] = __builtin_amdgcn_mfma_f32_16x16x32_bf16(a0, b0, acc[nt], 0, 0, 0);
        acc[nt] = __builtin_amdgcn_mfma_f32_16x16x32_bf16(a1, b1, acc[nt], 0, 0, 0);
    }
}

// ---------------- kernel 1: context + inverse rowsums ----------------
__global__ __launch_bounds__(256) void attn_ctx(
    const float* __restrict__ Q, const float* __restrict__ K,
    const float* __restrict__ V, const float* __restrict__ M,
    float* __restrict__ out, float* __restrict__ invg) {
    __shared__ unsigned char Qs[8192];
    __shared__ unsigned char Ks[8192];
    __shared__ unsigned char Vs[8192];   // transposed: [dcol][key]
    __shared__ unsigned char Ps[8192];

    const int tid = threadIdx.x;
    const int wv = tid >> 6, lane = tid & 63, lr = lane & 15, lg = lane >> 4;
    const int qt = blockIdx.x & 31, bh = blockIdx.x >> 5;

    const float* Qg = Q + ((size_t)bh * S_LEN + qt * 64) * D_KD;
    const float* Kg = K + (size_t)bh * S_LEN * D_KD;
    const float* Vg = V + (size_t)bh * S_LEN * D_KD;
    float* ctxg = out + ((size_t)bh * S_LEN + qt * 64) * D_KD;
    const float* Mg = M + (size_t)(qt * 64) * S_LEN;  // mask broadcast over bh

    stage_rm(Qg, Qs, tid);

    f32x4 accc[4] = {};
    float rs[4] = {0.f, 0.f, 0.f, 0.f};

    // prologue: tile 0 K/V into registers
    float4 kreg[4], vreg[4];
    load_rm(Kg, kreg, tid);
    load_tr(Vg, vreg, tid);

    for (int t = 0; t < NKT; t++) {
        // consume prefetched registers -> LDS (write-late half of T14)
        write_rm(kreg, Ks, tid);
        write_tr(vreg, Vs, tid);
        __syncthreads();

        // issue next tile's loads early (issue-early half of T14):
        // they have qkt + exp + PV (~1000+ cycles) to land.
        if (t + 1 < NKT) {
            load_rm(Kg + (size_t)(t + 1) * 64 * D_KD, kreg, tid);
            load_tr(Vg + (size_t)(t + 1) * 64 * D_KD, vreg, tid);
        }

        f32x4 acc[4] = {};
        qkt(Qs, Ks, wv, lr, lg, acc);

#pragma unroll
        for (int r = 0; r < 4; r++) {
            const int row = 16 * wv + 4 * lg + r;
            const float* mrow = Mg + (size_t)row * S_LEN + t * 64;
#pragma unroll
            for (int nt = 0; nt < 4; nt++) {
                float e = __expf(acc[nt][r] * 0.125f) * mrow[16 * nt + lr];
                rs[r] += e;
                *(unsigned short*)(Ps + swz(row, (16 * nt + lr) * 2)) = f2bf(e);
            }
        }
        __syncthreads();

#pragma unroll
        for (int kt = 0; kt < 2; kt++) {
            short8 pa = *(const short8*)(Ps + swz(16 * wv + lr, 16 * lg + 64 * kt));
#pragma unroll
            for (int nt = 0; nt < 4; nt++) {
                short8 vb = *(const short8*)(Vs + swz(16 * nt + lr, 16 * lg + 64 * kt));
                accc[nt] = __builtin_amdgcn_mfma_f32_16x16x32_bf16(pa, vb, accc[nt], 0, 0, 0);
            }
        }
        __syncthreads();   // Ks/Vs/Ps consumed before next write
    }

    float inv[4];
#pragma unroll
    for (int r = 0; r < 4; r++) {
        float v = rs[r];
        v += __shfl_xor(v, 1);
        v += __shfl_xor(v, 2);
        v += __shfl_xor(v, 4);
        v += __shfl_xor(v, 8);
        inv[r] = 1.0f / (v + 1e-8f);
    }

    // context write
#pragma unroll
    for (int r = 0; r < 4; r++) {
        const int row = 16 * wv + 4 * lg + r;
#pragma unroll
        for (int nt = 0; nt < 4; nt++)
            ctxg[(size_t)row * D_KD + 16 * nt + lr] = accc[nt][r] * inv[r];
    }

    // inv write (one lane per row group)
    if (lr == 0) {
#pragma unroll
        for (int r = 0; r < 4; r++)
            invg[(size_t)bh * S_LEN + qt * 64 + 16 * wv + 4 * lg + r] = inv[r];
    }
}

// ---------------- kernel 2: stream normalized attn (unchanged) ----------------
__global__ __launch_bounds__(256) void attn_mat(
    const float* __restrict__ Q, const float* __restrict__ K,
    const float* __restrict__ M, const float* __restrict__ invg,
    float* __restrict__ out) {
    __shared__ unsigned char Qs[8192];
    __shared__ unsigned char Ks[8192];

    const int tid = threadIdx.x;
    const int wv = tid >> 6, lane = tid & 63, lr = lane & 15, lg = lane >> 4;
    const int ks = blockIdx.x & (KSEG - 1);
    const int qt = (blockIdx.x >> 2) & 31;
    const int bh = blockIdx.x >> 7;

    const float* Qg = Q + ((size_t)bh * S_LEN + qt * 64) * D_KD;
    const float* Kg = K + (size_t)bh * S_LEN * D_KD;
    const float* Mg = M + (size_t)(qt * 64) * S_LEN;
    float* attng = out + (size_t)NBH * S_LEN * D_KD +
                   (size_t)bh * S_LEN * S_LEN + (size_t)(qt * 64) * S_LEN;

    stage_rm(Qg, Qs, tid);

    float inv[4];
#pragma unroll
    for (int r = 0; r < 4; r++)
        inv[r] = invg[(size_t)bh * S_LEN + qt * 64 + 16 * wv + 4 * lg + r];

    const int nt_kt = S_LEN / (64 * KSEG);   // 8 k-tiles per block
    for (int kt = 0; kt < nt_kt; kt++) {
        const int key0 = ks * (S_LEN / KSEG) + kt * 64;
        if (kt) __syncthreads();
        stage_rm(Kg + (size_t)key0 * D_KD, Ks, tid);
        __syncthreads();

        f32x4 acc[4] = {};
        qkt(Qs, Ks, wv, lr, lg, acc);

#pragma unroll
        for (int r = 0; r < 4; r++) {
            const int row = 16 * wv + 4 * lg + r;
            const float* mrow = Mg + (size_t)row * S_LEN + key0;
            float* arow = attng + (size_t)row * S_LEN + key0;
#pragma unroll
            for (int nt = 0; nt < 4; nt++) {
                float e = __expf(acc[nt][r] * 0.125f) * mrow[16 * nt + lr] * inv[r];
                __builtin_nontemporal_store(e, arow + 16 * nt + lr);
            }
        }
    }
}

extern "C" void kernel_launch(void* const* d_in, const int* in_sizes, int n_in,
                              void* d_out, int out_size, void* d_ws, size_t ws_size,
                              hipStream_t stream) {
    const float* Q = (const float*)d_in[0];
    const float* K = (const float*)d_in[1];
    const float* V = (const float*)d_in[2];
    const float* M = (const float*)d_in[3];
    float* out = (float*)d_out;
    float* invg = (float*)d_ws;          // 64*2048 floats = 512 KB
    attn_ctx<<<dim3(NBH * 32), dim3(256), 0, stream>>>(Q, K, V, M, out, invg);
    attn_mat<<<dim3(NBH * 32 * KSEG), dim3(256), 0, stream>>>(Q, K, M, invg, out);
}

// Round 7
// 461.289 us; speedup vs baseline: 1.1245x; 1.0754x over previous
//
// v6: raw s_barrier + lgkmcnt-only waits (no vmcnt drain in loops) in BOTH
//     kernels; mask loads grouped into regs before QK^T. Else identical to v5.
#include <hip/hip_runtime.h>

#define S_LEN 2048
#define D_KD  64
#define NKT   32          // S / 64 k-tiles
#define NBH   64          // B*H
#define KSEG  4           // kernel2: key segments per (bh,qt)

typedef __attribute__((ext_vector_type(8))) short short8;   // 8 bf16 (4 VGPRs)
typedef __attribute__((ext_vector_type(4))) float f32x4;    // MFMA C/D

// ---- bf16 round-to-nearest-even from f32 ----
__device__ __forceinline__ unsigned short f2bf(float f) {
    unsigned u = __builtin_bit_cast(unsigned, f);
    return (unsigned short)((u + 0x7fffu + ((u >> 16) & 1u)) >> 16);
}

// Cross-wave LDS-visibility barrier WITHOUT vmcnt drain (8-phase template
// pattern): my ds_writes/ds_reads are complete before I cross; in-flight
// global loads/stores (vmcnt) keep flying.
__device__ __forceinline__ void ldsbar() {
    asm volatile("s_waitcnt lgkmcnt(0)" ::: "memory");
    __builtin_amdgcn_s_barrier();
}

// ---- XOR swizzle for [64][64] bf16 tiles (row stride 128B).
__device__ __forceinline__ unsigned swz(int row, int bytecol) {
    return (unsigned)(row * 128 + bytecol) ^
           (((((unsigned)row & 7u) ^ ((unsigned)row >> 3)) & 7u) << 4);
}

// ---- register-staged tile load/write (T14 split) ----
__device__ __forceinline__ void load_rm(const float* __restrict__ g,
                                        float4 r[4], int tid) {
#pragma unroll
    for (int j = 0; j < 4; j++) r[j] = *(const float4*)(g + j * 1024 + tid * 4);
}
__device__ __forceinline__ void write_rm(const float4 r[4],
                                         unsigned char* lds, int tid) {
#pragma unroll
    for (int j = 0; j < 4; j++) {
        int idx = j * 1024 + tid * 4;
        int row = idx >> 6, col = idx & 63;
        ushort4 b = make_ushort4(f2bf(r[j].x), f2bf(r[j].y), f2bf(r[j].z), f2bf(r[j].w));
        *(ushort4*)(lds + swz(row, col * 2)) = b;
    }
}
__device__ __forceinline__ void load_tr(const float* __restrict__ g,
                                        float4 r[4], int tid) {
    const int br = tid >> 4, bc = tid & 15;
    const float* gp = g + (4 * br) * 64 + 4 * bc;
#pragma unroll
    for (int j = 0; j < 4; j++) r[j] = *(const float4*)(gp + j * 64);
}
__device__ __forceinline__ void write_tr(const float4 r[4],
                                         unsigned char* lds, int tid) {
    const int br = tid >> 4, bc = tid & 15;
    ushort4 c;
    c = make_ushort4(f2bf(r[0].x), f2bf(r[1].x), f2bf(r[2].x), f2bf(r[3].x));
    *(ushort4*)(lds + swz(4 * bc + 0, 8 * br)) = c;
    c = make_ushort4(f2bf(r[0].y), f2bf(r[1].y), f2bf(r[2].y), f2bf(r[3].y));
    *(ushort4*)(lds + swz(4 * bc + 1, 8 * br)) = c;
    c = make_ushort4(f2bf(r[0].z), f2bf(r[1].z), f2bf(r[2].z), f2bf(r[3].z));
    *(ushort4*)(lds + swz(4 * bc + 2, 8 * br)) = c;
    c = make_ushort4(f2bf(r[0].w), f2bf(r[1].w), f2bf(r[2].w), f2bf(r[3].w));
    *(ushort4*)(lds + swz(4 * bc + 3, 8 * br)) = c;
}

// Stage a contiguous 64x64 f32 tile -> bf16 row-major swizzled LDS.
__device__ __forceinline__ void stage_rm(const float* __restrict__ g,
                                         unsigned char* lds, int tid) {
    float4 r[4];
    load_rm(g, r, tid);
    write_rm(r, lds, tid);
}

// 64x64 QK^T for this wave's 16-row slice.
__device__ __forceinline__ void qkt(const unsigned char* Qs, const unsigned char* Ks,
                                    int wv, int lr, int lg, f32x4 acc[4]) {
    short8 a0 = *(const short8*)(Qs + swz(16 * wv + lr, 16 * lg));
    short8 a1 = *(const short8*)(Qs + swz(16 * wv + lr, 16 * lg + 64));
#pragma unroll
    for (int nt = 0; nt < 4; nt++) {
        short8 b0 = *(const short8*)(Ks + swz(16 * nt + lr, 16 * lg));
        short8 b1 = *(const short8*)(Ks + swz(16 * nt + lr, 16 * lg + 64));
        acc[nt] = __builtin_amdgcn_mfma_f32_16x16x32_bf16(a0, b0, acc[nt], 0, 0, 0);
        acc[nt] = __builtin_amdgcn_mfma_f32_16x16x32_bf16(a1, b1, acc[nt], 0, 0, 0);
    }
}

// ---------------- kernel 1: context + inverse rowsums ----------------
__global__ __launch_bounds__(256) void attn_ctx(
    const float* __restrict__ Q, const float* __restrict__ K,
    const float* __restrict__ V, const float* __restrict__ M,
    float* __restrict__ out, float* __restrict__ invg) {
    __shared__ unsigned char Qs[8192];
    __shared__ unsigned char Ks[8192];
    __shared__ unsigned char Vs[8192];   // transposed: [dcol][key]
    __shared__ unsigned char Ps[8192];

    const int tid = threadIdx.x;
    const int wv = tid >> 6, lane = tid & 63, lr = lane & 15, lg = lane >> 4;
    const int qt = blockIdx.x & 31, bh = blockIdx.x >> 5;

    const float* Qg = Q + ((size_t)bh * S_LEN + qt * 64) * D_KD;
    const float* Kg = K + (size_t)bh * S_LEN * D_KD;
    const float* Vg = V + (size_t)bh * S_LEN * D_KD;
    float* ctxg = out + ((size_t)bh * S_LEN + qt * 64) * D_KD;
    const float* Mg = M + (size_t)(qt * 64) * S_LEN;  // mask broadcast over bh

    stage_rm(Qg, Qs, tid);

    f32x4 accc[4] = {};
    float rs[4] = {0.f, 0.f, 0.f, 0.f};

    // prologue: tile 0 K/V into registers
    float4 kreg[4], vreg[4];
    load_rm(Kg, kreg, tid);
    load_tr(Vg, vreg, tid);

    for (int t = 0; t < NKT; t++) {
        // consume prefetched registers -> LDS
        write_rm(kreg, Ks, tid);
        write_tr(vreg, Vs, tid);
        ldsbar();                             // staging visible; vm stays in flight

        // issue next tile's loads: they have qkt+exp+PV (2 barriers, no
        // vmcnt drain) to land.
        if (t + 1 < NKT) {
            load_rm(Kg + (size_t)(t + 1) * 64 * D_KD, kreg, tid);
            load_tr(Vg + (size_t)(t + 1) * 64 * D_KD, vreg, tid);
        }

        // mask values for this tile, grouped so they overlap the MFMAs
        float mreg[4][4];
#pragma unroll
        for (int r = 0; r < 4; r++) {
            const float* mrow = Mg + (size_t)(16 * wv + 4 * lg + r) * S_LEN + t * 64;
#pragma unroll
            for (int nt = 0; nt < 4; nt++) mreg[r][nt] = mrow[16 * nt + lr];
        }

        f32x4 acc[4] = {};
        qkt(Qs, Ks, wv, lr, lg, acc);

#pragma unroll
        for (int r = 0; r < 4; r++) {
            const int row = 16 * wv + 4 * lg + r;
#pragma unroll
            for (int nt = 0; nt < 4; nt++) {
                float e = __expf(acc[nt][r] * 0.125f) * mreg[r][nt];
                rs[r] += e;
                *(unsigned short*)(Ps + swz(row, (16 * nt + lr) * 2)) = f2bf(e);
            }
        }
        ldsbar();                             // P visible; prefetch still flying

#pragma unroll
        for (int kt = 0; kt < 2; kt++) {
            short8 pa = *(const short8*)(Ps + swz(16 * wv + lr, 16 * lg + 64 * kt));
#pragma unroll
            for (int nt = 0; nt < 4; nt++) {
                short8 vb = *(const short8*)(Vs + swz(16 * nt + lr, 16 * lg + 64 * kt));
                accc[nt] = __builtin_amdgcn_mfma_f32_16x16x32_bf16(pa, vb, accc[nt], 0, 0, 0);
            }
        }
        ldsbar();                             // all reads done before next overwrite
    }

    float inv[4];
#pragma unroll
    for (int r = 0; r < 4; r++) {
        float v = rs[r];
        v += __shfl_xor(v, 1);
        v += __shfl_xor(v, 2);
        v += __shfl_xor(v, 4);
        v += __shfl_xor(v, 8);
        inv[r] = 1.0f / (v + 1e-8f);
    }

    // context write
#pragma unroll
    for (int r = 0; r < 4; r++) {
        const int row = 16 * wv + 4 * lg + r;
#pragma unroll
        for (int nt = 0; nt < 4; nt++)
            ctxg[(size_t)row * D_KD + 16 * nt + lr] = accc[nt][r] * inv[r];
    }

    // inv write (one lane per row group)
    if (lr == 0) {
#pragma unroll
        for (int r = 0; r < 4; r++)
            invg[(size_t)bh * S_LEN + qt * 64 + 16 * wv + 4 * lg + r] = inv[r];
    }
}

// ---------------- kernel 2: stream normalized attn ----------------
__global__ __launch_bounds__(256) void attn_mat(
    const float* __restrict__ Q, const float* __restrict__ K,
    const float* __restrict__ M, const float* __restrict__ invg,
    float* __restrict__ out) {
    __shared__ unsigned char Qs[8192];
    __shared__ unsigned char Ks[8192];

    const int tid = threadIdx.x;
    const int wv = tid >> 6, lane = tid & 63, lr = lane & 15, lg = lane >> 4;
    const int ks = blockIdx.x & (KSEG - 1);
    const int qt = (blockIdx.x >> 2) & 31;
    const int bh = blockIdx.x >> 7;

    const float* Qg = Q + ((size_t)bh * S_LEN + qt * 64) * D_KD;
    const float* Kg = K + (size_t)bh * S_LEN * D_KD;
    const float* Mg = M + (size_t)(qt * 64) * S_LEN;
    float* attng = out + (size_t)NBH * S_LEN * D_KD +
                   (size_t)bh * S_LEN * S_LEN + (size_t)(qt * 64) * S_LEN;

    stage_rm(Qg, Qs, tid);

    float inv[4];
#pragma unroll
    for (int r = 0; r < 4; r++)
        inv[r] = invg[(size_t)bh * S_LEN + qt * 64 + 16 * wv + 4 * lg + r];

    const int nt_kt = S_LEN / (64 * KSEG);   // 8 k-tiles per block
    const float* Kseg = Kg + (size_t)(ks * (S_LEN / KSEG)) * D_KD;

    float4 kreg[4];
    load_rm(Kseg, kreg, tid);                // prologue prefetch

    for (int kt = 0; kt < nt_kt; kt++) {
        const int key0 = ks * (S_LEN / KSEG) + kt * 64;
        write_rm(kreg, Ks, tid);             // consume prefetch
        ldsbar();                            // staging visible; stores keep flying

        if (kt + 1 < nt_kt)
            load_rm(Kseg + (size_t)(kt + 1) * 64 * D_KD, kreg, tid);

        float mreg[4][4];
#pragma unroll
        for (int r = 0; r < 4; r++) {
            const float* mrow = Mg + (size_t)(16 * wv + 4 * lg + r) * S_LEN + key0;
#pragma unroll
            for (int nt = 0; nt < 4; nt++) mreg[r][nt] = mrow[16 * nt + lr];
        }

        f32x4 acc[4] = {};
        qkt(Qs, Ks, wv, lr, lg, acc);

#pragma unroll
        for (int r = 0; r < 4; r++) {
            const int row = 16 * wv + 4 * lg + r;
            float* arow = attng + (size_t)row * S_LEN + key0;
#pragma unroll
            for (int nt = 0; nt < 4; nt++) {
                float e = __expf(acc[nt][r] * 0.125f) * mreg[r][nt] * inv[r];
                __builtin_nontemporal_store(e, arow + 16 * nt + lr);
            }
        }
        ldsbar();                            // qkt ds_reads done before overwrite
    }
}

extern "C" void kernel_launch(void* const* d_in, const int* in_sizes, int n_in,
                              void* d_out, int out_size, void* d_ws, size_t ws_size,
                              hipStream_t stream) {
    const float* Q = (const float*)d_in[0];
    const float* K = (const float*)d_in[1];
    const float* V = (const float*)d_in[2];
    const float* M = (const float*)d_in[3];
    float* out = (float*)d_out;
    float* invg = (float*)d_ws;          // 64*2048 floats = 512 KB
    attn_ctx<<<dim3(NBH * 32), dim3(256), 0, stream>>>(Q, K, V, M, out, invg);
    attn_mat<<<dim3(NBH * 32 * KSEG), dim3(256), 0, stream>>>(Q, K, M, invg, out);
}